// Round 9
// baseline (85.837 us; speedup 1.0000x reference)
//
#include <hip/hip_runtime.h>
#include <math.h>

#define S_LEN  2048
#define D_HEAD 128
#define QBLK   64
#define KVBLK  64
#define BATCH  16
#define NKVT   (S_LEN / KVBLK)     // 32 kv tiles per batch
#define TILE_SH 8192               // shorts per 64x128 tile image (16 KB)

typedef __attribute__((ext_vector_type(4))) float f32x4;
typedef __attribute__((ext_vector_type(8))) short short8;

__device__ __forceinline__ unsigned short f2bf(float x) {
    union { float f; unsigned u; } v; v.f = x;
    unsigned r = v.u + 0x7fffu + ((v.u >> 16) & 1u);
    return (unsigned short)(r >> 16);
}
__device__ __forceinline__ float bf2f(unsigned short h) {
    union { unsigned u; float f; } v; v.u = ((unsigned)h) << 16;
    return v.f;
}
__device__ __forceinline__ unsigned pack2(unsigned short a, unsigned short b) {
    return (unsigned)a | ((unsigned)b << 16);
}
__device__ __forceinline__ unsigned cvtpk(float lo, float hi) {
    unsigned r;
    asm("v_cvt_pk_bf16_f32 %0, %1, %2" : "=v"(r) : "v"(lo), "v"(hi));
    return r;
}
__device__ __forceinline__ void gld16(const void* g, void* l) {
    __builtin_amdgcn_global_load_lds(
        (const __attribute__((address_space(1))) void*)g,
        (__attribute__((address_space(3))) void*)l, 16, 0, 0);
}
template<int N> __device__ __forceinline__ void wait_vm() {
    asm volatile("s_waitcnt vmcnt(%0)" :: "i"(N) : "memory");
}
__device__ __forceinline__ void barrier() {
    __builtin_amdgcn_sched_barrier(0);
    __builtin_amdgcn_s_barrier();
    __builtin_amdgcn_sched_barrier(0);
}

// prep: one block per (batch, kv-tile). Emits PRE-SWIZZLED contiguous LDS images.
__global__ __launch_bounds__(256) void prep(const float* __restrict__ K,
                                            const float* __restrict__ V,
                                            unsigned short* __restrict__ Kp,
                                            unsigned short* __restrict__ Vp)
{
    const int tid = threadIdx.x;
    const int bid = blockIdx.x;
    const int b = bid >> 5, t = bid & 31;
    const size_t ibase = (size_t)b * S_LEN * D_HEAD + (size_t)t * KVBLK * D_HEAD;
    unsigned short* ko = Kp + (size_t)bid * TILE_SH;
    unsigned short* vo = Vp + (size_t)bid * TILE_SH;

    #pragma unroll
    for (int c = 0; c < 4; ++c) {
        int i  = c * 256 + tid;
        int k  = i >> 4;
        int d8 = ((i & 15) * 8) ^ ((k & 7) << 3);
        const float* sp = K + ibase + (size_t)k * D_HEAD + d8;
        float4 a = *(const float4*)sp;
        float4 bb = *(const float4*)(sp + 4);
        uint4 u = { pack2(f2bf(a.x),f2bf(a.y)),  pack2(f2bf(a.z),f2bf(a.w)),
                    pack2(f2bf(bb.x),f2bf(bb.y)),pack2(f2bf(bb.z),f2bf(bb.w)) };
        *(uint4*)(ko + i * 8) = u;
    }

    __shared__ unsigned short Vb[KVBLK][D_HEAD + 2];
    {
        const int r  = tid >> 2;
        const int c0 = (tid & 3) * 32;
        const float* sp = V + ibase + (size_t)r * D_HEAD + c0;
        #pragma unroll
        for (int i = 0; i < 8; ++i) {
            float4 x = *(const float4*)(sp + i * 4);
            Vb[r][c0+i*4+0] = f2bf(x.x); Vb[r][c0+i*4+1] = f2bf(x.y);
            Vb[r][c0+i*4+2] = f2bf(x.z); Vb[r][c0+i*4+3] = f2bf(x.w);
        }
    }
    __syncthreads();
    #pragma unroll
    for (int c = 0; c < 4; ++c) {
        int i   = c * 256 + tid;
        int d   = i >> 3;
        int kk0 = ((i & 7) * 8) ^ ((d & 7) << 3);
        unsigned short h[8];
        #pragma unroll
        for (int j = 0; j < 8; ++j) h[j] = Vb[kk0 + j][d];
        uint4 u = { pack2(h[0],h[1]), pack2(h[2],h[3]), pack2(h[4],h[5]), pack2(h[6],h[7]) };
        *(uint4*)(vo + i * 8) = u;
    }
}

// Paired kernel: 512 blocks x 512 threads. bid = o*16 + b (XCD = b%8).
// Job o -> (pair p, chunk ci): o<16: j=o else j=47-o; p=j>>1, ci=j&1 (desc/asc
// ordering so blocks c and c+256 have complementary chunk lengths).
// Waves 0-3 own qb=p, waves 4-7 own qb=31-p; shared K/V stream over strided
// tiles t = ci, ci+2, ... < 32-p. Both emit bf16 partials + (m,l).
__global__ __launch_bounds__(512, 4)
void attn_paired(const float* __restrict__ Qg, const unsigned short* __restrict__ Kp,
                 const unsigned short* __restrict__ Vp,
                 unsigned short* __restrict__ Po, float* __restrict__ Ml)
{
    constexpr float CSC = 0.12751744f;      // log2(e)/sqrt(128), folded into Q
    const int tid  = threadIdx.x;
    const int lane = tid & 63;
    const int w8   = tid >> 6;              // 0..7
    const int w4   = w8 & 3;
    const bool hi  = w8 >= 4;
    const int bid  = blockIdx.x;
    const int b    = bid & 15;
    const int o    = bid >> 4;              // 0..31
    const int j    = (o < 16) ? o : (47 - o);
    const int p    = j >> 1, ci = j & 1;
    const int L    = 32 - p;                // joint range
    const int len  = (L - ci + 1) >> 1;     // tiles in this chunk (strided by 2)

    const int qbw  = hi ? (31 - p) : p;
    const int q0w  = qbw * QBLK + w4 * 16;
    const int qc   = lane & 15;
    const int g    = lane >> 4;
    const int qidx = q0w + qc;

    __shared__ __align__(16) unsigned short Klds[TILE_SH];        // 16 KB
    __shared__ __align__(16) unsigned short Vlds[TILE_SH];        // 16 KB
    __shared__ __align__(16) unsigned short Plds[8][16 * KVBLK];  // 16 KB

    const size_t base = (size_t)b * S_LEN * D_HEAD;
    const int tb = b * NKVT;

    auto stage_K = [&](int t) {             // 2 DMA issues/wave (8 waves cover 16KB)
        const unsigned short* ks = Kp + (size_t)(tb + t) * TILE_SH + w8 * 512 + lane * 8;
        gld16(ks,        &Klds[w8 * 512 + lane * 8]);
        gld16(ks + 4096, &Klds[4096 + w8 * 512 + lane * 8]);
    };
    auto stage_V = [&](int t) {
        const unsigned short* vs = Vp + (size_t)(tb + t) * TILE_SH + w8 * 512 + lane * 8;
        gld16(vs,        &Vlds[w8 * 512 + lane * 8]);
        gld16(vs + 4096, &Vlds[4096 + w8 * 512 + lane * 8]);
    };

    stage_K(ci);
    stage_V(ci);

    // ---- Q fragments (MFMA B operand), pre-scaled ----
    short8 qf[4];
    {
        const float* qp = Qg + base + (size_t)(q0w + qc) * D_HEAD + g * 8;
        #pragma unroll
        for (int db = 0; db < 4; ++db) {
            float4 x0 = *(const float4*)(qp + db * 32);
            float4 x1 = *(const float4*)(qp + db * 32 + 4);
            float tt[8] = {x0.x, x0.y, x0.z, x0.w, x1.x, x1.y, x1.z, x1.w};
            short8 f;
            #pragma unroll
            for (int jj = 0; jj < 8; ++jj) f[jj] = (short)f2bf(tt[jj] * CSC);
            qf[db] = f;
        }
    }

    f32x4 acc[8] = {};                      // acc[db][r] = O[q=4g+r][d=db*16+qc]
    float m = -1e30f, lsum = 0.f;           // lane-partial lsum

    for (int i = 0; i < len; ++i) {
        const int t   = ci + 2 * i;
        const int kv0 = t * KVBLK;
        const bool more = (i + 1 < len);

        // K[t] landed in every wave before anyone reads it
        wait_vm<2>();
        barrier();

        const int t16max = min(3, (q0w + 15 - kv0) >> 4);   // <0 => wave inactive
        const int ksmax  = min(1, (q0w + 15 - kv0) >> 5);
        const bool active = t16max >= 0;                    // wave-uniform

        f32x4 st[4] = {};
        if (active) {
            __builtin_amdgcn_s_setprio(1);
            #pragma unroll
            for (int t16 = 0; t16 < 4; ++t16) {
                if (t16 <= t16max) {
                    const int kr = t16 * 16 + qc;
                    const int swz = (kr & 7) << 3;
                    #pragma unroll
                    for (int db = 0; db < 4; ++db) {
                        short8 kf = *(const short8*)&Klds[(kr * 128 + db * 32 + g * 8) ^ swz];
                        st[t16] = __builtin_amdgcn_mfma_f32_16x16x32_bf16(kf, qf[db], st[t16], 0, 0, 0);
                    }
                }
            }
            __builtin_amdgcn_s_setprio(0);
        }

        barrier();                           // all waves done reading Klds
        if (more) stage_K(t + 2);            // K DMA hides under softmax + PV

        float p16[16];
        if (active) {
            float s[16];
            #pragma unroll
            for (int t16 = 0; t16 < 4; ++t16)
                #pragma unroll
                for (int r = 0; r < 4; ++r)
                    s[t16*4+r] = (t16 <= t16max) ? st[t16][r] : -1e30f;

            if (kv0 + KVBLK - 1 > q0w) {     // diagonal: per-lane causal mask
                #pragma unroll
                for (int t16 = 0; t16 < 4; ++t16)
                    #pragma unroll
                    for (int r = 0; r < 4; ++r)
                        if (kv0 + t16 * 16 + g * 4 + r > qidx) s[t16*4+r] = -1e30f;
            }

            float m0 = fmaxf(fmaxf(s[0],s[1]), fmaxf(s[2],s[3]));
            float m1 = fmaxf(fmaxf(s[4],s[5]), fmaxf(s[6],s[7]));
            float m2 = fmaxf(fmaxf(s[8],s[9]), fmaxf(s[10],s[11]));
            float m3 = fmaxf(fmaxf(s[12],s[13]), fmaxf(s[14],s[15]));
            float mx = fmaxf(fmaxf(m0,m1), fmaxf(m2,m3));

            if (__any(mx > m + 8.0f)) {
                mx = fmaxf(mx, __shfl_xor(mx, 16));
                mx = fmaxf(mx, __shfl_xor(mx, 32));
                float mnew = fmaxf(m, mx);
                float alpha = exp2f(m - mnew);
                m = mnew;
                lsum *= alpha;
                float a_o[4];
                #pragma unroll
                for (int r = 0; r < 4; ++r) a_o[r] = __shfl(alpha, g * 4 + r);
                #pragma unroll
                for (int db = 0; db < 8; ++db)
                    #pragma unroll
                    for (int r = 0; r < 4; ++r) acc[db][r] *= a_o[r];
            }

            #pragma unroll
            for (int ii = 0; ii < 16; ++ii) p16[ii] = exp2f(s[ii] - m);
            float r0 = (p16[0]+p16[1]) + (p16[2]+p16[3]);
            float r1 = (p16[4]+p16[5]) + (p16[6]+p16[7]);
            float r2 = (p16[8]+p16[9]) + (p16[10]+p16[11]);
            float r3 = (p16[12]+p16[13]) + (p16[14]+p16[15]);
            lsum += (r0+r1) + (r2+r3);
        }

        // V[t] landed in every wave before anyone reads it
        if (more) wait_vm<2>(); else wait_vm<0>();
        barrier();

        if (active) {
            const int pswz = (qc & 7) << 3;
            #pragma unroll
            for (int t16 = 0; t16 < 4; ++t16) {
                uint2 uu = { cvtpk(p16[t16*4+0], p16[t16*4+1]), cvtpk(p16[t16*4+2], p16[t16*4+3]) };
                *(uint2*)&Plds[w8][(qc * 64 + t16 * 16 + g * 4) ^ pswz] = uu;
            }
            __builtin_amdgcn_s_setprio(1);
            #pragma unroll
            for (int ks = 0; ks < 2; ++ks) {
                if (ks <= ksmax) {
                    short8 pa = *(const short8*)&Plds[w8][(qc * 64 + ks * 32 + g * 8) ^ pswz];
                    #pragma unroll
                    for (int db = 0; db < 8; ++db) {
                        const int d = db * 16 + qc;
                        short8 vf = *(const short8*)&Vlds[(d * 64 + ks * 32 + g * 8) ^ ((d & 7) << 3)];
                        acc[db] = __builtin_amdgcn_mfma_f32_16x16x32_bf16(pa, vf, acc[db], 0, 0, 0);
                    }
                }
            }
            __builtin_amdgcn_s_setprio(0);
        }

        barrier();                           // all waves done reading Vlds
        if (more) stage_V(t + 2);            // V DMA hides under next QK^T
    }

    // ---- epilogue: bf16 partials + (m, l) ----
    lsum += __shfl_xor(lsum, 16);
    lsum += __shfl_xor(lsum, 32);

    const int pslot = ((((b << 4) | p) * 2 + ci) << 1) + (hi ? 1 : 0);
    unsigned short* po = Po + (size_t)pslot * (QBLK * D_HEAD);
    #pragma unroll
    for (int db = 0; db < 8; ++db)
        #pragma unroll
        for (int r = 0; r < 4; ++r)
            po[(w4 * 16 + g * 4 + r) * D_HEAD + db * 16 + qc] = f2bf(acc[db][r]);
    if (g == 0) {
        float* ml = Ml + (size_t)pslot * (QBLK * 2);
        ml[(w4 * 16 + qc) * 2 + 0] = m;
        ml[(w4 * 16 + qc) * 2 + 1] = lsum;
    }
}

// combine the two chunks of every q-block (all 32 per batch)
__global__ __launch_bounds__(256)
void combine(const unsigned short* __restrict__ Po, const float* __restrict__ Ml,
             float* __restrict__ Og)
{
    const int z   = blockIdx.x;             // qb*16 + b  (XCD = b%8)
    const int b   = z & 15;
    const int qb  = z >> 4;                 // 0..31
    const int tid = threadIdx.x;
    const int row = tid >> 2;
    const int c0  = (tid & 3) * 32;

    const int set = (qb > 15) ? 1 : 0;
    const int p   = set ? (31 - qb) : qb;
    const int pA  = ((((b << 4) | p) * 2 + 0) << 1) + set;
    const int pB  = ((((b << 4) | p) * 2 + 1) << 1) + set;

    const float* mlA = Ml + (size_t)pA * (QBLK * 2);
    const float* mlB = Ml + (size_t)pB * (QBLK * 2);
    const float mA = mlA[row*2], lA = mlA[row*2+1];
    const float mB = mlB[row*2], lB = mlB[row*2+1];
    const float M  = fmaxf(mA, mB);
    const float aA = exp2f(mA - M), aB = exp2f(mB - M);
    const float rd = 1.0f / (aA * lA + aB * lB);

    const unsigned short* poA = Po + (size_t)pA * (QBLK * D_HEAD) + row * D_HEAD + c0;
    const unsigned short* poB = Po + (size_t)pB * (QBLK * D_HEAD) + row * D_HEAD + c0;
    float* op = Og + (size_t)b * S_LEN * D_HEAD + (size_t)(qb * QBLK + row) * D_HEAD + c0;

    #pragma unroll
    for (int jj = 0; jj < 4; ++jj) {
        uint4 ua = *(const uint4*)(poA + jj * 8);
        uint4 ub = *(const uint4*)(poB + jj * 8);
        const unsigned short* ha = (const unsigned short*)&ua;
        const unsigned short* hb = (const unsigned short*)&ub;
        float4 o0, o1;
        o0.x = (aA*bf2f(ha[0]) + aB*bf2f(hb[0])) * rd;
        o0.y = (aA*bf2f(ha[1]) + aB*bf2f(hb[1])) * rd;
        o0.z = (aA*bf2f(ha[2]) + aB*bf2f(hb[2])) * rd;
        o0.w = (aA*bf2f(ha[3]) + aB*bf2f(hb[3])) * rd;
        o1.x = (aA*bf2f(ha[4]) + aB*bf2f(hb[4])) * rd;
        o1.y = (aA*bf2f(ha[5]) + aB*bf2f(hb[5])) * rd;
        o1.z = (aA*bf2f(ha[6]) + aB*bf2f(hb[6])) * rd;
        o1.w = (aA*bf2f(ha[7]) + aB*bf2f(hb[7])) * rd;
        *(float4*)(op + jj * 8)     = o0;
        *(float4*)(op + jj * 8 + 4) = o1;
    }
}

// fallback (small ws): 512 blocks x 256 threads, complementary pairing, direct O.
__global__ __launch_bounds__(256, 2)
void attn_direct(const float* __restrict__ Qg, const unsigned short* __restrict__ Kp,
                 const unsigned short* __restrict__ Vp, float* __restrict__ Og)
{
    constexpr float CSC = 0.12751744f;
    const int tid  = threadIdx.x;
    const int lane = tid & 63;
    const int w    = tid >> 6;
    const int bid  = blockIdx.x;
    const int b    = bid & 15;
    const int rank = bid >> 4;
    const int qb   = (rank < 16) ? (31 - rank) : (rank - 16);
    const int q0w  = qb * QBLK + w * 16;
    const int qc   = lane & 15;
    const int g    = lane >> 4;
    const int qidx = q0w + qc;

    __shared__ __align__(16) unsigned short Klds[TILE_SH];
    __shared__ __align__(16) unsigned short Vlds[TILE_SH];
    __shared__ __align__(16) unsigned short Plds[4][16 * KVBLK];

    const size_t base = (size_t)b * S_LEN * D_HEAD;
    const int tb = b * NKVT;

    auto stage_K = [&](int t) {
        const unsigned short* ks = Kp + (size_t)(tb + t) * TILE_SH + w * 2048 + lane * 8;
        #pragma unroll
        for (int ii = 0; ii < 4; ++ii) gld16(ks + ii * 512, &Klds[w * 2048 + ii * 512]);
    };
    auto stage_V = [&](int t) {
        const unsigned short* vs = Vp + (size_t)(tb + t) * TILE_SH + w * 2048 + lane * 8;
        #pragma unroll
        for (int ii = 0; ii < 4; ++ii) gld16(vs + ii * 512, &Vlds[w * 2048 + ii * 512]);
    };

    short8 qf[4];
    {
        const float* qp = Qg + base + (size_t)(q0w + qc) * D_HEAD + g * 8;
        #pragma unroll
        for (int db = 0; db < 4; ++db) {
            float4 x0 = *(const float4*)(qp + db * 32);
            float4 x1 = *(const float4*)(qp + db * 32 + 4);
            float tt[8] = {x0.x, x0.y, x0.z, x0.w, x1.x, x1.y, x1.z, x1.w};
            short8 f;
            #pragma unroll
            for (int jj = 0; jj < 8; ++jj) f[jj] = (short)f2bf(tt[jj] * CSC);
            qf[db] = f;
        }
    }

    f32x4 acc[8] = {};
    float m = -1e30f, lsum = 0.f;
    const int nt = qb + 1;

    stage_K(0);
    stage_V(0);

    for (int t = 0; t < nt; ++t) {
        const int kv0 = t * KVBLK;
        const bool more = (t + 1 < nt);
        wait_vm<4>();
        barrier();

        const int t16max = min(3, (q0w + 15 - kv0) >> 4);
        const int ksmax  = min(1, (q0w + 15 - kv0) >> 5);

        f32x4 st[4] = {};
        __builtin_amdgcn_s_setprio(1);
        #pragma unroll
        for (int t16 = 0; t16 < 4; ++t16) {
            if (t16 <= t16max) {
                const int kr = t16 * 16 + qc;
                const int swz = (kr & 7) << 3;
                #pragma unroll
                for (int db = 0; db < 4; ++db) {
                    short8 kf = *(const short8*)&Klds[(kr * 128 + db * 32 + g * 8) ^ swz];
                    st[t16] = __builtin_amdgcn_mfma_f32_16x16x32_bf16(kf, qf[db], st[t16], 0, 0, 0);
                }
            }
        }
        __builtin_amdgcn_s_setprio(0);
        barrier();
        if (more) stage_K(t + 1);

        float s[16];
        #pragma unroll
        for (int t16 = 0; t16 < 4; ++t16)
            #pragma unroll
            for (int r = 0; r < 4; ++r)
                s[t16*4+r] = (t16 <= t16max) ? st[t16][r] : -1e30f;
        if (kv0 + KVBLK - 1 > q0w) {
            #pragma unroll
            for (int t16 = 0; t16 < 4; ++t16)
                #pragma unroll
                for (int r = 0; r < 4; ++r)
                    if (kv0 + t16 * 16 + g * 4 + r > qidx) s[t16*4+r] = -1e30f;
        }
        float m0 = fmaxf(fmaxf(s[0],s[1]), fmaxf(s[2],s[3]));
        float m1 = fmaxf(fmaxf(s[4],s[5]), fmaxf(s[6],s[7]));
        float m2 = fmaxf(fmaxf(s[8],s[9]), fmaxf(s[10],s[11]));
        float m3 = fmaxf(fmaxf(s[12],s[13]), fmaxf(s[14],s[15]));
        float mx = fmaxf(fmaxf(m0,m1), fmaxf(m2,m3));
        if (__any(mx > m + 8.0f)) {
            mx = fmaxf(mx, __shfl_xor(mx, 16));
            mx = fmaxf(mx, __shfl_xor(mx, 32));
            float mnew = fmaxf(m, mx);
            float alpha = exp2f(m - mnew);
            m = mnew;
            lsum *= alpha;
            float a_o[4];
            #pragma unroll
            for (int r = 0; r < 4; ++r) a_o[r] = __shfl(alpha, g * 4 + r);
            #pragma unroll
            for (int db = 0; db < 8; ++db)
                #pragma unroll
                for (int r = 0; r < 4; ++r) acc[db][r] *= a_o[r];
        }
        float p16[16];
        #pragma unroll
        for (int ii = 0; ii < 16; ++ii) p16[ii] = exp2f(s[ii] - m);
        float r0 = (p16[0]+p16[1]) + (p16[2]+p16[3]);
        float r1 = (p16[4]+p16[5]) + (p16[6]+p16[7]);
        float r2 = (p16[8]+p16[9]) + (p16[10]+p16[11]);
        float r3 = (p16[12]+p16[13]) + (p16[14]+p16[15]);
        lsum += (r0+r1) + (r2+r3);

        if (more) wait_vm<4>(); else wait_vm<0>();
        barrier();

        const int pswz = (qc & 7) << 3;
        #pragma unroll
        for (int t16 = 0; t16 < 4; ++t16) {
            uint2 uu = { cvtpk(p16[t16*4+0], p16[t16*4+1]), cvtpk(p16[t16*4+2], p16[t16*4+3]) };
            *(uint2*)&Plds[w][(qc * 64 + t16 * 16 + g * 4) ^ pswz] = uu;
        }
        __builtin_amdgcn_s_setprio(1);
        #pragma unroll
        for (int ks = 0; ks < 2; ++ks) {
            if (ks <= ksmax) {
                short8 pa = *(const short8*)&Plds[w][(qc * 64 + ks * 32 + g * 8) ^ pswz];
                #pragma unroll
                for (int db = 0; db < 8; ++db) {
                    const int d = db * 16 + qc;
                    short8 vf = *(const short8*)&Vlds[(d * 64 + ks * 32 + g * 8) ^ ((d & 7) << 3)];
                    acc[db] = __builtin_amdgcn_mfma_f32_16x16x32_bf16(pa, vf, acc[db], 0, 0, 0);
                }
            }
        }
        __builtin_amdgcn_s_setprio(0);
        barrier();
        if (more) stage_V(t + 1);
    }

    lsum += __shfl_xor(lsum, 16);
    lsum += __shfl_xor(lsum, 32);
    float linv = 1.0f / lsum;
    float li[4];
    #pragma unroll
    for (int r = 0; r < 4; ++r) li[r] = __shfl(linv, g * 4 + r);
    #pragma unroll
    for (int db = 0; db < 8; ++db)
        #pragma unroll
        for (int r = 0; r < 4; ++r)
            Og[base + (size_t)(q0w + g * 4 + r) * D_HEAD + db * 16 + qc] = acc[db][r] * li[r];
}

extern "C" void kernel_launch(void* const* d_in, const int* in_sizes, int n_in,
                              void* d_out, int out_size, void* d_ws, size_t ws_size,
                              hipStream_t stream) {
    const float* Q = (const float*)d_in[0];
    const float* K = (const float*)d_in[1];
    const float* V = (const float*)d_in[2];
    float* O = (float*)d_out;

    const size_t tile_elems = (size_t)BATCH * NKVT * TILE_SH;
    unsigned short* Kp = (unsigned short*)d_ws;
    unsigned short* Vp = Kp + tile_elems;
    unsigned short* Po = Vp + tile_elems;                       // 1024 * 8192 bf16
    float*          Mlp = (float*)(Po + (size_t)1024 * QBLK * D_HEAD);
    const size_t need_bytes = (char*)(Mlp + (size_t)1024 * QBLK * 2) - (char*)d_ws;

    prep<<<dim3(BATCH * NKVT), dim3(256), 0, stream>>>(K, V, Kp, Vp);
    if (ws_size >= need_bytes) {
        attn_paired<<<dim3(512), dim3(512), 0, stream>>>(Q, Kp, Vp, Po, Mlp);
        combine<<<dim3(32 * BATCH), dim3(256), 0, stream>>>(Po, Mlp, O);
    } else {
        attn_direct<<<dim3(512), dim3(256), 0, stream>>>(Q, Kp, Vp, O);
    }
}